// Round 12
// baseline (296.196 us; speedup 1.0000x reference)
//
#include <hip/hip_runtime.h>
#include <hip/hip_bf16.h>
#include <cstdint>

// Problem constants
#define B_ 4
#define N_ 2048
#define C_ 768
#define H_ 12
#define D_ 64
// SCALE = D^-0.5 = 0.125; folded exp2 scale = 0.125 * log2(e)
#define QSCALE 0.18033688011112042f

typedef __bf16 bf16x8 __attribute__((ext_vector_type(8)));
typedef float f32x4 __attribute__((ext_vector_type(4)));
typedef float f32x16 __attribute__((ext_vector_type(16)));

// RNE float -> bf16 bits (branchless; inputs are finite)
__device__ __forceinline__ unsigned f2bs(float x) {
  unsigned u = __builtin_bit_cast(unsigned, x);
  unsigned r = (u + 0x7fffu + ((u >> 16) & 1u)) >> 16;
  return r;
}

__device__ __forceinline__ bf16x8 ldb8(const unsigned short* p) {
  return __builtin_bit_cast(bf16x8, *(const uint4*)p);
}

__device__ __forceinline__ f32x4 mfma16(bf16x8 a, bf16x8 b, f32x4 c) {
  return __builtin_amdgcn_mfma_f32_16x16x32_bf16(a, b, c, 0, 0, 0);
}

__device__ __forceinline__ f32x16 mfma32(bf16x8 a, bf16x8 b, f32x16 c) {
  return __builtin_amdgcn_mfma_f32_32x32x16_bf16(a, b, c, 0, 0, 0);
}

// async global->LDS, 16B per lane. lds base must be wave-uniform; HW deposits
// lane i at lds + i*16 (m97/m104 semantics).
__device__ __forceinline__ void async16(const unsigned short* g, unsigned short* l) {
  __builtin_amdgcn_global_load_lds(
      (const __attribute__((address_space(1))) unsigned int*)g,
      (__attribute__((address_space(3))) unsigned int*)l, 16, 0, 0);
}

// pack two f32 -> one dword of 2 bf16 (RNE; identical numerics to f2bs)
__device__ __forceinline__ unsigned pkbf(float lo, float hi) {
  unsigned d;
  asm("v_cvt_pk_bf16_f32 %0, %1, %2" : "=v"(d) : "v"(lo), "v"(hi));
  return d;
}

// ---------------- prep (R12: W casts + uc only; x-conversion fused into qkv) ------
// blocks [0,576): convert Wq/Wk/Wv/Wp (144 blocks each, 4096 floats/block)
// blocks [576,2624): uc[row] = mean(x_u row) (2048 blocks, 4 rows each)
__global__ void prep_kernel(
    const float* __restrict__ xu,
    const float* __restrict__ Wq, const float* __restrict__ Wk,
    const float* __restrict__ Wv, const float* __restrict__ Wp,
    unsigned short* __restrict__ dwq, unsigned short* __restrict__ dwk,
    unsigned short* __restrict__ dwv, unsigned short* __restrict__ dwp,
    float* __restrict__ uc) {
  const int id = blockIdx.x;
  if (id < 576) {
    int which = id / 144;
    const float* s = (which == 0) ? Wq : (which == 1) ? Wk : (which == 2) ? Wv : Wp;
    unsigned short* d = (which == 0) ? dwq : (which == 1) ? dwk : (which == 2) ? dwv : dwp;
    int sub = id - which * 144;
    const int base = sub * 4096 + (int)threadIdx.x * 4;
#pragma unroll
    for (int st = 0; st < 4; ++st) {
      int i = base + st * 1024;
      float4 v = *(const float4*)(s + i);
      ushort4 h;
      h.x = (unsigned short)f2bs(v.x); h.y = (unsigned short)f2bs(v.y);
      h.z = (unsigned short)f2bs(v.z); h.w = (unsigned short)f2bs(v.w);
      *(ushort4*)(d + i) = h;
    }
  } else {
    int sub = id - 576;
    int w = threadIdx.x >> 6, lane = threadIdx.x & 63;
    int row = sub * 4 + w;
    const float* p = xu + (size_t)row * C_;
    float s = 0.f;
#pragma unroll
    for (int i = 0; i < 3; ++i) {
      float4 v = *(const float4*)(p + (i * 64 + lane) * 4);
      s += v.x + v.y + v.z + v.w;
    }
#pragma unroll
    for (int off = 1; off < 64; off <<= 1) s += __shfl_xor(s, off);
    if (lane == 0) uc[row] = s * (1.f / 768.f);
  }
}

// ---------------- fused QKV projection, BN=192, f32-A fused cast (R12) ------------
// R10 structure (BN=192, BK=64, 768 blocks = 3/CU, single-buffer, 48 MFMA/barrier
// pair) measured best. R12 fuses the x f32->bf16 cast into A-staging: A is read in
// f32 and converted with v_cvt_pk_bf16_f32 (RNE == f2bs) into the SAME LDS layout.
// Kills prep's 75.5MB x-read + 37.7MB x-write + qkv's 37.7MB bf16 re-read round
// trip. B/W path keeps async16. R11's BK=32 counted-vmcnt pipeline REVERTED
// (measured neutral-negative: doubled barriers canceled hidden latency).
// z=0: Q = x_q@Wq^T * QSCALE*uc; z=1: K; z=2: V^T via LDS transpose, coalesced.
#define TSTR 136   // transpose LDS row stride (shorts): 272 B, 16B-aligned rows
__global__ __launch_bounds__(256, 3) void gemm_qkv(
    const float* __restrict__ xqf, const float* __restrict__ xkf,
    const float* __restrict__ xvf,
    const unsigned short* __restrict__ wq, const unsigned short* __restrict__ wk,
    const unsigned short* __restrict__ wv,
    unsigned short* __restrict__ oq, unsigned short* __restrict__ ok,
    unsigned short* __restrict__ ov, const float* __restrict__ uc) {
  __shared__ __align__(16) unsigned short S[192 * TSTR];   // 52224 B; aliases Al/Bl
  unsigned short* Al = S;                                  // 128x64 = 8192 shorts
  unsigned short* Bl = S + 8192;                           // 192x64 = 12288 shorts
  const int tid = threadIdx.x;
  const int w = tid >> 6, lane = tid & 63, quad = lane >> 4, id15 = lane & 15;
  const int wm = (w >> 1) << 6, wn = (w & 1) * 96;
  // XCD swizzle: xcd = id&7; within an XCD, n varies fastest for fixed (z,m)
  const int id = blockIdx.x;
  const int xcd = id & 7, slot = id >> 3;          // slot 0..95
  const int n0 = (slot & 3) * 192;                 // 4 n-blocks of 192
  const int gz = xcd * 24 + (slot >> 2);           // 0..191 = (z,m) pairs
  const int z = gz >> 6, m0 = (gz & 63) << 7;

  const float* A32 = (z == 0) ? xqf : (z == 1) ? xkf : xvf;
  const unsigned short* W = (z == 0) ? wq : (z == 1) ? wk : wv;

  const int wb = tid & 192;                        // wave-uniform granule base
  // A: 128 rows x 64 cols = 1024 granules (4 sets); granule = 8 elems; f32 source.
  // dest shorts [g*8..g*8+8); src row=(g>>2)&127, col=((g>>9)<<5)|((g&3)<<3)
  const float* ap[4];
  int adst[4];
#pragma unroll
  for (int s = 0; s < 4; ++s) {
    int g = s * 256 + tid;
    int row = (g >> 2) & 127;
    int col = ((g >> 9) << 5) | ((g & 3) << 3);
    ap[s] = A32 + (size_t)(m0 + row) * C_ + col;
    adst[s] = g * 8;
  }
  // B: 192 rows x 64 cols = 1536 granules (6 sets); panel pan = g>=768 (no mask!)
  const unsigned short* bp[6];
#pragma unroll
  for (int s = 0; s < 6; ++s) {
    int g = s * 256 + tid;
    int r4 = g >> 2;
    int pan = (g >= 768) ? 1 : 0;
    int row = r4 - pan * 192;
    int col = pan * 32 + ((g & 3) << 3);
    bp[s] = W + (size_t)(n0 + row) * C_ + col;
  }

  f32x4 acc[4][6] = {};
  for (int kt = 0; kt < C_; kt += 64) {
    __syncthreads();
#pragma unroll
    for (int s = 0; s < 6; ++s) async16(bp[s] + kt, Bl + (s * 256 + wb) * 8);
    // A: reg-staged f32 -> bf16 cvt_pk -> ds_write (same layout async16 produced)
#pragma unroll
    for (int s = 0; s < 4; ++s) {
      float4 u0 = *(const float4*)(ap[s] + kt);
      float4 u1 = *(const float4*)(ap[s] + kt + 4);
      uint4 pk;
      pk.x = pkbf(u0.x, u0.y);
      pk.y = pkbf(u0.z, u0.w);
      pk.z = pkbf(u1.x, u1.y);
      pk.w = pkbf(u1.z, u1.w);
      *(uint4*)&Al[adst[s]] = pk;
    }
    __syncthreads();

#pragma unroll
    for (int kk = 0; kk < 2; ++kk) {
      bf16x8 af[4], bfr[6];
#pragma unroll
      for (int i = 0; i < 4; ++i)
        af[i]  = ldb8(&Al[kk * 4096 + (wm + i * 16 + id15) * 32 + quad * 8]);
#pragma unroll
      for (int j = 0; j < 6; ++j)
        bfr[j] = ldb8(&Bl[kk * 6144 + (wn + j * 16 + id15) * 32 + quad * 8]);
#pragma unroll
      for (int i = 0; i < 4; ++i)
#pragma unroll
        for (int j = 0; j < 6; ++j)
          acc[i][j] = mfma16(af[i], bfr[j], acc[i][j]);
    }
  }

  if (z == 2) {
    // transpose through LDS: S[gn_local][n_local], then coalesced row writes
    __syncthreads();
#pragma unroll
    for (int i = 0; i < 4; ++i)
#pragma unroll
      for (int j = 0; j < 6; ++j) {
        uint2 u;
        u.x = f2bs(acc[i][j][0]) | (f2bs(acc[i][j][1]) << 16);
        u.y = f2bs(acc[i][j][2]) | (f2bs(acc[i][j][3]) << 16);
        *(uint2*)&S[(wn + j * 16 + id15) * TSTR + wm + i * 16 + quad * 4] = u;
      }
    __syncthreads();
    const int b = m0 >> 11, nb2 = m0 & (N_ - 1);
#pragma unroll
    for (int s = 0; s < 12; ++s) {
      int c = s * 256 + tid;               // 3072 chunks of 8 shorts (192 rows)
      int row = c >> 4, o = (c & 15) << 3;
      *(uint4*)(ov + (size_t)(b * C_ + n0 + row) * N_ + nb2 + o) = *(const uint4*)&S[row * TSTR + o];
    }
    return;
  }

#pragma unroll
  for (int i = 0; i < 4; ++i) {
#pragma unroll
    for (int j = 0; j < 6; ++j) {
#pragma unroll
      for (int r = 0; r < 4; ++r) {
        int gm = m0 + wm + i * 16 + quad * 4 + r;   // global row (b*N + n)
        int gn = n0 + wn + j * 16 + id15;           // global out channel
        float v = acc[i][j][r];
        if (z == 0) {
          v *= QSCALE * uc[gm];
          oq[(size_t)gm * C_ + gn] = (unsigned short)f2bs(v);
        } else {
          ok[(size_t)gm * C_ + gn] = (unsigned short)f2bs(v);
        }
      }
    }
  }
}

// ---------------- output projection: out = ao@Wp^T + bp, f32 (R10 form) -----------
// Tile 64(M) x 128(N), BK=64 -> 768 blocks = 3/CU.
// XCD swizzle: same-A-tile blocks (6 n) on one XCD.
__global__ __launch_bounds__(256, 4) void gemm_out(
    const unsigned short* __restrict__ ao, const unsigned short* __restrict__ wp,
    float* __restrict__ out, const float* __restrict__ bias) {
  __shared__ __align__(16) unsigned short Al[64 * 64];
  __shared__ __align__(16) unsigned short Bl[128 * 64];
  const int tid = threadIdx.x;
  const int w = tid >> 6, lane = tid & 63, quad = lane >> 4, id15 = lane & 15;
  const int wm = (w >> 1) << 5, wn = (w & 1) << 6;
  const int id = blockIdx.x;
  const int xcd = id & 7, slot = id >> 3;          // slot 0..95
  const int n0 = (slot % 6) << 7;
  const int m0 = (xcd * 16 + slot / 6) << 6;       // m-tile 0..127

  const int wb = tid & 192;
  const unsigned short* ap[2];
#pragma unroll
  for (int s = 0; s < 2; ++s) {                    // A: 64x64 tile, 512 granules
    int g = s * 256 + tid;
    int row = (g >> 2) & 63;
    int col = ((g >> 8) << 5) | ((g & 3) << 3);
    ap[s] = ao + (size_t)(m0 + row) * C_ + col;
  }
  const unsigned short* bp[4];
#pragma unroll
  for (int s = 0; s < 4; ++s) {                    // B: 128x64 tile, 1024 granules
    int g = s * 256 + tid;
    int row = (g >> 2) & 127;
    int col = ((g >> 9) << 5) | ((g & 3) << 3);
    bp[s] = wp + (size_t)(n0 + row) * C_ + col;
  }

  f32x4 acc[2][4] = {};
  for (int kt = 0; kt < C_; kt += 64) {
    __syncthreads();
#pragma unroll
    for (int s = 0; s < 2; ++s) async16(ap[s] + kt, Al + (s * 256 + wb) * 8);
#pragma unroll
    for (int s = 0; s < 4; ++s) async16(bp[s] + kt, Bl + (s * 256 + wb) * 8);
    __syncthreads();

#pragma unroll
    for (int kk = 0; kk < 2; ++kk) {
      bf16x8 af[2], bfr[4];
#pragma unroll
      for (int i = 0; i < 2; ++i)
        af[i]  = ldb8(&Al[kk * 2048 + (wm + i * 16 + id15) * 32 + quad * 8]);
#pragma unroll
      for (int j = 0; j < 4; ++j)
        bfr[j] = ldb8(&Bl[kk * 4096 + (wn + j * 16 + id15) * 32 + quad * 8]);
#pragma unroll
      for (int i = 0; i < 2; ++i)
#pragma unroll
        for (int j = 0; j < 4; ++j)
          acc[i][j] = mfma16(af[i], bfr[j], acc[i][j]);
    }
  }

#pragma unroll
  for (int i = 0; i < 2; ++i) {
#pragma unroll
    for (int j = 0; j < 4; ++j) {
#pragma unroll
      for (int r = 0; r < 4; ++r) {
        int gm = m0 + wm + i * 16 + quad * 4 + r;
        int gn = n0 + wn + j * 16 + id15;
        out[(size_t)gm * C_ + gn] = acc[i][j][r] + bias[gn];
      }
    }
  }
}

// ---------------- Flash attention v4 (R4/R9/R10-measured, ~84-86us) ---------------
// Coalesced K+V LDS double-buffer + raw s_barrier with lgkmcnt-only drain (next-tile
// loads stay in flight across the barrier), permlane32_swap P-repack, ones-MFMA
// row-sum, setprio around MFMA clusters.
// C/D layout (m74/m101): col=lane&31, row=(reg&3)+8*(reg>>2)+4*(lane>>5).
#define KSTR 72   // K/V LDS row stride (shorts): 144 B
#define VOFF (64 * KSTR)        // V panel offset within a buffer (shorts)
#define BUFO (2 * 64 * KSTR)    // double-buffer stride (shorts); LDS = 36864 B
__global__ __launch_bounds__(256, 3) void attn_kernel(
    const unsigned short* __restrict__ Q, const unsigned short* __restrict__ Kk,
    const unsigned short* __restrict__ Vt, unsigned short* __restrict__ O) {
  __shared__ __align__(16) unsigned short KV[2 * 2 * 64 * KSTR];  // 36864 B

  const int tid = threadIdx.x;
  const int w = tid >> 6, lane = tid & 63;
  const int i32 = lane & 31, hi = lane >> 5;
  const int id = blockIdx.x;
  const int xcd = id & 7, slot = id >> 3;          // slot 0..95
  const int bh = xcd * 6 + (slot >> 4);            // 0..47
  const int qt = slot & 15;
  const int b = bh / H_, h = bh % H_;
  const int q0 = qt * 128 + w * 32;                // 32 q-rows per wave

  // Q fragments (B-operand of QK^T): qf[s] = Q[q0+i32][d = s*16 + hi*8 + e]
  bf16x8 qf[4];
#pragma unroll
  for (int s = 0; s < 4; ++s)
    qf[s] = ldb8(Q + (size_t)(b * N_ + q0 + i32) * C_ + h * 64 + s * 16 + hi * 8);

  const uint4 onesu = {0x3F803F80u, 0x3F803F80u, 0x3F803F80u, 0x3F803F80u};
  const bf16x8 onesf = __builtin_bit_cast(bf16x8, onesu);

  f32x16 oacc0 = {}, oacc1 = {}, lacc = {};

  const size_t kbase = (size_t)(b * N_) * C_ + h * 64;
  const size_t vbase = (size_t)(b * C_ + h * 64) * N_;
  const int srow0 = tid >> 3, srow1 = 32 + (tid >> 3);
  const int sseg = (tid & 7) << 3;

  // Prologue: stage K+V tile 0 into buffer 0 (coalesced reg->LDS)
  {
    uint4 a0 = *(const uint4*)(Kk + kbase + (size_t)srow0 * C_ + sseg);
    uint4 a1 = *(const uint4*)(Kk + kbase + (size_t)srow1 * C_ + sseg);
    uint4 c0 = *(const uint4*)(Vt + vbase + (size_t)srow0 * N_ + sseg);
    uint4 c1 = *(const uint4*)(Vt + vbase + (size_t)srow1 * N_ + sseg);
    *(uint4*)&KV[srow0 * KSTR + sseg] = a0;
    *(uint4*)&KV[srow1 * KSTR + sseg] = a1;
    *(uint4*)&KV[VOFF + srow0 * KSTR + sseg] = c0;
    *(uint4*)&KV[VOFF + srow1 * KSTR + sseg] = c1;
  }

  int cur = 0;
  for (int kc = 0; kc < N_; kc += 64) {
    // next K+V tile -> regs, issued at iter top; they stay in flight across the
    // raw barrier (no vmcnt drain) and land in LDS after compute.
    const bool last = (kc + 64 >= N_);
    uint4 a0, a1, c0, c1;
    if (!last) {
      const int kcn = kc + 64;
      a0 = *(const uint4*)(Kk + kbase + (size_t)(kcn + srow0) * C_ + sseg);
      a1 = *(const uint4*)(Kk + kbase + (size_t)(kcn + srow1) * C_ + sseg);
      c0 = *(const uint4*)(Vt + vbase + (size_t)srow0 * N_ + kcn + sseg);
      c1 = *(const uint4*)(Vt + vbase + (size_t)srow1 * N_ + kcn + sseg);
    }

    // drain own LDS ops (prev writes + frag reads), then barrier. NO vmcnt drain.
    asm volatile("s_waitcnt lgkmcnt(0)" ::: "memory");
    __builtin_amdgcn_s_barrier();

    const unsigned short* Kc = KV + (cur ? BUFO : 0);
    const unsigned short* Vc = Kc + VOFF;
#pragma unroll
    for (int t = 0; t < 2; ++t) {        // k-row tile of 32 within the 64-row block
      // QK^T (S^T: rows = k, cols = q), contraction over D=64 in 4 ksteps
      f32x16 s16 = {};
      __builtin_amdgcn_s_setprio(1);
#pragma unroll
      for (int s = 0; s < 4; ++s) {
        bf16x8 kf = ldb8(Kc + (t * 32 + i32) * KSTR + s * 16 + hi * 8);
        s16 = mfma32(kf, qf[s], s16);
      }
      __builtin_amdgcn_s_setprio(0);
      // exp2 + RNE pack: dword j = P(k-pair start 8*(j>>1)+2*(j&1)+4*hi, col q=i32)
      unsigned Dw[8];
#pragma unroll
      for (int j = 0; j < 8; ++j) {
        float e0 = exp2f(s16[2 * j]);
        float e1 = exp2f(s16[2 * j + 1]);
        unsigned d;
        asm("v_cvt_pk_bf16_f32 %0, %1, %2" : "=v"(d) : "v"(e0), "v"(e1));
        Dw[j] = d;
      }
      // Half-swap repack into PV A-frags via permlane32_swap, then lsum + PV.
      __builtin_amdgcn_s_setprio(1);
#pragma unroll
      for (int sl = 0; sl < 2; ++sl) {
        const int bb = sl * 4;
        unsigned x0 = Dw[bb + 0], y0 = Dw[bb + 2];
        unsigned x1 = Dw[bb + 1], y1 = Dw[bb + 3];
        asm("v_permlane32_swap_b32 %0, %1" : "+v"(x0), "+v"(y0));
        asm("v_permlane32_swap_b32 %0, %1" : "+v"(x1), "+v"(y1));
        uint4 u;
        u.x = x0;                        // e0,e1: k = 16*sl + 8*hi + {0,1}
        u.y = x1;                        // e2,e3: +2
        u.z = y0;                        // e4,e5: +4
        u.w = y1;                        // e6,e7: +6
        bf16x8 pf = __builtin_bit_cast(bf16x8, u);
        lacc = mfma32(pf, onesf, lacc);  // row-sum on the matrix pipe
        bf16x8 v0 = ldb8(Vc + i32 * KSTR + (2 * t + sl) * 16 + hi * 8);
        bf16x8 v1 = ldb8(Vc + (32 + i32) * KSTR + (2 * t + sl) * 16 + hi * 8);
        oacc0 = mfma32(pf, v0, oacc0);
        oacc1 = mfma32(pf, v1, oacc1);
      }
      __builtin_amdgcn_s_setprio(0);
    }

    if (!last) {
      unsigned short* Kn = KV + (cur ? 0 : BUFO);
      *(uint4*)&Kn[srow0 * KSTR + sseg] = a0;
      *(uint4*)&Kn[srow1 * KSTR + sseg] = a1;
      *(uint4*)&Kn[VOFF + srow0 * KSTR + sseg] = c0;
      *(uint4*)&Kn[VOFF + srow1 * KSTR + sseg] = c1;
    }
    cur ^= 1;
  }

  // Epilogue: lacc reg r holds l for the same q-row as oacc reg r.
#pragma unroll
  for (int r = 0; r < 16; ++r) {
    float linv = 1.0f / lacc[r];
    int q = q0 + (r & 3) + 8 * (r >> 2) + 4 * hi;
    size_t base = (size_t)(b * N_ + q) * C_ + h * 64 + i32;
    O[base] = (unsigned short)f2bs(oacc0[r] * linv);
    O[base + 32] = (unsigned short)f2bs(oacc1[r] * linv);
  }
}

extern "C" void kernel_launch(void* const* d_in, const int* in_sizes, int n_in,
                              void* d_out, int out_size, void* d_ws, size_t ws_size,
                              hipStream_t stream) {
  const float* x_q = (const float*)d_in[0];
  const float* x_k = (const float*)d_in[1];
  const float* x_v = (const float*)d_in[2];
  const float* x_u = (const float*)d_in[3];
  const float* Wq  = (const float*)d_in[4];
  const float* Wk  = (const float*)d_in[5];
  const float* Wv  = (const float*)d_in[6];
  const float* Wp  = (const float*)d_in[7];
  const float* bp  = (const float*)d_in[8];

  char* ws = (char*)d_ws;
  size_t off = 0;
  auto alloc = [&](size_t bytes) {
    char* p = ws + off;
    off += (bytes + 255) & ~(size_t)255;
    return p;
  };
  unsigned short* wq16 = (unsigned short*)alloc((size_t)C_ * C_ * 2);
  unsigned short* wk16 = (unsigned short*)alloc((size_t)C_ * C_ * 2);
  unsigned short* wv16 = (unsigned short*)alloc((size_t)C_ * C_ * 2);
  unsigned short* wp16 = (unsigned short*)alloc((size_t)C_ * C_ * 2);
  float*          ucp  = (float*)alloc((size_t)B_ * N_ * 4);
  unsigned short* q_s  = (unsigned short*)alloc((size_t)B_ * N_ * C_ * 2);
  unsigned short* k_s  = (unsigned short*)alloc((size_t)B_ * N_ * C_ * 2);
  unsigned short* vT   = (unsigned short*)alloc((size_t)B_ * N_ * C_ * 2);
  unsigned short* ao   = (unsigned short*)alloc((size_t)B_ * N_ * C_ * 2);

  prep_kernel<<<dim3(2624), 256, 0, stream>>>(x_u, Wq, Wk, Wv, Wp,
                                              wq16, wk16, wv16, wp16, ucp);
  gemm_qkv<<<dim3(768), 256, 0, stream>>>(x_q, x_k, x_v, wq16, wk16, wv16,
                                          q_s, k_s, vT, ucp);
  attn_kernel<<<dim3(768), 256, 0, stream>>>(q_s, k_s, vT, ao);
  gemm_out<<<dim3(768), 256, 0, stream>>>(ao, wp16, (float*)d_out, bp);
}

// Round 13
// 282.219 us; speedup vs baseline: 1.0495x; 1.0495x over previous
//
#include <hip/hip_runtime.h>
#include <hip/hip_bf16.h>
#include <cstdint>

// Problem constants
#define B_ 4
#define N_ 2048
#define C_ 768
#define H_ 12
#define D_ 64
// SCALE = D^-0.5 = 0.125; folded exp2 scale = 0.125 * log2(e)
#define QSCALE 0.18033688011112042f

typedef __bf16 bf16x8 __attribute__((ext_vector_type(8)));
typedef float f32x4 __attribute__((ext_vector_type(4)));
typedef float f32x16 __attribute__((ext_vector_type(16)));

// RNE float -> bf16 bits (branchless; inputs are finite)
__device__ __forceinline__ unsigned f2bs(float x) {
  unsigned u = __builtin_bit_cast(unsigned, x);
  unsigned r = (u + 0x7fffu + ((u >> 16) & 1u)) >> 16;
  return r;
}

__device__ __forceinline__ bf16x8 ldb8(const unsigned short* p) {
  return __builtin_bit_cast(bf16x8, *(const uint4*)p);
}

__device__ __forceinline__ f32x4 mfma16(bf16x8 a, bf16x8 b, f32x4 c) {
  return __builtin_amdgcn_mfma_f32_16x16x32_bf16(a, b, c, 0, 0, 0);
}

__device__ __forceinline__ f32x16 mfma32(bf16x8 a, bf16x8 b, f32x16 c) {
  return __builtin_amdgcn_mfma_f32_32x32x16_bf16(a, b, c, 0, 0, 0);
}

// async global->LDS, 16B per lane. lds base must be wave-uniform; HW deposits
// lane i at lds + i*16 (m97/m104 semantics).
__device__ __forceinline__ void async16(const unsigned short* g, unsigned short* l) {
  __builtin_amdgcn_global_load_lds(
      (const __attribute__((address_space(1))) unsigned int*)g,
      (__attribute__((address_space(3))) unsigned int*)l, 16, 0, 0);
}

// ---------------- fused prep: x/W f32->bf16 casts + uc row means ----------------
// Coarsened to 64 B/thread (4 coalesced float4 steps).
// blocks [0,4608): convert x_q/x_k/x_v (1536 blocks each, 4096 floats/block)
// blocks [4608,5184): convert Wq/Wk/Wv/Wp (144 blocks each)
// blocks [5184,7232): uc[row] = mean(x_u row) (2048 blocks, 4 rows each)
__global__ void prep_kernel(
    const float* __restrict__ xq, const float* __restrict__ xk,
    const float* __restrict__ xv, const float* __restrict__ xu,
    const float* __restrict__ Wq, const float* __restrict__ Wk,
    const float* __restrict__ Wv, const float* __restrict__ Wp,
    unsigned short* __restrict__ dxq, unsigned short* __restrict__ dxk,
    unsigned short* __restrict__ dxv,
    unsigned short* __restrict__ dwq, unsigned short* __restrict__ dwk,
    unsigned short* __restrict__ dwv, unsigned short* __restrict__ dwp,
    float* __restrict__ uc) {
  const int id = blockIdx.x;
  if (id < 5184) {
    const float* s;
    unsigned short* d;
    int sub;
    if (id < 4608) {
      s = (id < 1536) ? xq : (id < 3072) ? xk : xv;
      d = (id < 1536) ? dxq : (id < 3072) ? dxk : dxv;
      sub = (id < 1536) ? id : (id < 3072) ? (id - 1536) : (id - 3072);
    } else {
      int t = id - 4608;
      int which = t / 144;
      s = (which == 0) ? Wq : (which == 1) ? Wk : (which == 2) ? Wv : Wp;
      d = (which == 0) ? dwq : (which == 1) ? dwk : (which == 2) ? dwv : dwp;
      sub = t % 144;
    }
    const int base = sub * 4096 + (int)threadIdx.x * 4;
#pragma unroll
    for (int st = 0; st < 4; ++st) {
      int i = base + st * 1024;
      float4 v = *(const float4*)(s + i);
      ushort4 h;
      h.x = (unsigned short)f2bs(v.x); h.y = (unsigned short)f2bs(v.y);
      h.z = (unsigned short)f2bs(v.z); h.w = (unsigned short)f2bs(v.w);
      *(ushort4*)(d + i) = h;
    }
  } else {
    int sub = id - 5184;
    int w = threadIdx.x >> 6, lane = threadIdx.x & 63;
    int row = sub * 4 + w;
    const float* p = xu + (size_t)row * C_;
    float s = 0.f;
#pragma unroll
    for (int i = 0; i < 3; ++i) {
      float4 v = *(const float4*)(p + (i * 64 + lane) * 4);
      s += v.x + v.y + v.z + v.w;
    }
#pragma unroll
    for (int off = 1; off < 64; off <<= 1) s += __shfl_xor(s, off);
    if (lane == 0) uc[row] = s * (1.f / 768.f);
  }
}

// ---------------- fused QKV projection, BN=192 (R10-measured best) ----------------
// Tile 128x192, 2x2 waves each 64x96, 768 blocks = exactly 3/CU. A staged 4x,
// 48 MFMA per barrier-pair. LDS: Al 16K + Bl 24K; z=2 transpose buffer
// 192x136x2 = 52224 B (3 blocks/CU = 156.7 KB <= 160).
// R12's fused f32-A cast REVERTED (qkv went 90us, latency-bound: reg-staged f32
// loads exposed between barriers + 2x A bytes + 3.1M bank conflicts).
// R11's BK=32 counted-vmcnt REVERTED (halved MFMA-per-barrier canceled the gain).
// Non-pow2 row decode uses explicit compare-subtract (R8 lesson: no &-masking).
// z=0: Q = x_q@Wq^T * QSCALE*uc; z=1: K; z=2: V^T via LDS transpose, coalesced.
#define TSTR 136   // transpose LDS row stride (shorts): 272 B, 16B-aligned rows
__global__ __launch_bounds__(256, 3) void gemm_qkv(
    const unsigned short* __restrict__ xq, const unsigned short* __restrict__ xk,
    const unsigned short* __restrict__ xv,
    const unsigned short* __restrict__ wq, const unsigned short* __restrict__ wk,
    const unsigned short* __restrict__ wv,
    unsigned short* __restrict__ oq, unsigned short* __restrict__ ok,
    unsigned short* __restrict__ ov, const float* __restrict__ uc) {
  __shared__ __align__(16) unsigned short S[192 * TSTR];   // 52224 B; aliases Al/Bl
  unsigned short* Al = S;                                  // 128x64 = 8192 shorts
  unsigned short* Bl = S + 8192;                           // 192x64 = 12288 shorts
  const int tid = threadIdx.x;
  const int w = tid >> 6, lane = tid & 63, quad = lane >> 4, id15 = lane & 15;
  const int wm = (w >> 1) << 6, wn = (w & 1) * 96;
  // XCD swizzle: xcd = id&7; within an XCD, n varies fastest for fixed (z,m)
  const int id = blockIdx.x;
  const int xcd = id & 7, slot = id >> 3;          // slot 0..95
  const int n0 = (slot & 3) * 192;                 // 4 n-blocks of 192
  const int gz = xcd * 24 + (slot >> 2);           // 0..191 = (z,m) pairs
  const int z = gz >> 6, m0 = (gz & 63) << 7;

  const unsigned short* A = (z == 0) ? xq : (z == 1) ? xk : xv;
  const unsigned short* W = (z == 0) ? wq : (z == 1) ? wk : wv;

  const int wb = tid & 192;                        // wave-uniform granule base
  // A: 128 rows x 64 cols = 1024 granules (4 sets); panel kk = g>=512
  const unsigned short* ap[4];
#pragma unroll
  for (int s = 0; s < 4; ++s) {
    int g = s * 256 + tid;
    int row = (g >> 2) & 127;
    int col = ((g >> 9) << 5) | ((g & 3) << 3);
    ap[s] = A + (size_t)(m0 + row) * C_ + col;
  }
  // B: 192 rows x 64 cols = 1536 granules (6 sets); panel pan = g>=768 (no mask!)
  const unsigned short* bp[6];
#pragma unroll
  for (int s = 0; s < 6; ++s) {
    int g = s * 256 + tid;
    int r4 = g >> 2;
    int pan = (g >= 768) ? 1 : 0;
    int row = r4 - pan * 192;
    int col = pan * 32 + ((g & 3) << 3);
    bp[s] = W + (size_t)(n0 + row) * C_ + col;
  }

  f32x4 acc[4][6] = {};
  for (int kt = 0; kt < C_; kt += 64) {
    __syncthreads();
#pragma unroll
    for (int s = 0; s < 4; ++s) async16(ap[s] + kt, Al + (s * 256 + wb) * 8);
#pragma unroll
    for (int s = 0; s < 6; ++s) async16(bp[s] + kt, Bl + (s * 256 + wb) * 8);
    __syncthreads();

#pragma unroll
    for (int kk = 0; kk < 2; ++kk) {
      bf16x8 af[4], bfr[6];
#pragma unroll
      for (int i = 0; i < 4; ++i)
        af[i]  = ldb8(&Al[kk * 4096 + (wm + i * 16 + id15) * 32 + quad * 8]);
#pragma unroll
      for (int j = 0; j < 6; ++j)
        bfr[j] = ldb8(&Bl[kk * 6144 + (wn + j * 16 + id15) * 32 + quad * 8]);
#pragma unroll
      for (int i = 0; i < 4; ++i)
#pragma unroll
        for (int j = 0; j < 6; ++j)
          acc[i][j] = mfma16(af[i], bfr[j], acc[i][j]);
    }
  }

  if (z == 2) {
    // transpose through LDS: S[gn_local][n_local], then coalesced row writes
    __syncthreads();
#pragma unroll
    for (int i = 0; i < 4; ++i)
#pragma unroll
      for (int j = 0; j < 6; ++j) {
        uint2 u;
        u.x = f2bs(acc[i][j][0]) | (f2bs(acc[i][j][1]) << 16);
        u.y = f2bs(acc[i][j][2]) | (f2bs(acc[i][j][3]) << 16);
        *(uint2*)&S[(wn + j * 16 + id15) * TSTR + wm + i * 16 + quad * 4] = u;
      }
    __syncthreads();
    const int b = m0 >> 11, nb2 = m0 & (N_ - 1);
#pragma unroll
    for (int s = 0; s < 12; ++s) {
      int c = s * 256 + tid;               // 3072 chunks of 8 shorts (192 rows)
      int row = c >> 4, o = (c & 15) << 3;
      *(uint4*)(ov + (size_t)(b * C_ + n0 + row) * N_ + nb2 + o) = *(const uint4*)&S[row * TSTR + o];
    }
    return;
  }

#pragma unroll
  for (int i = 0; i < 4; ++i) {
#pragma unroll
    for (int j = 0; j < 6; ++j) {
#pragma unroll
      for (int r = 0; r < 4; ++r) {
        int gm = m0 + wm + i * 16 + quad * 4 + r;   // global row (b*N + n)
        int gn = n0 + wn + j * 16 + id15;           // global out channel
        float v = acc[i][j][r];
        if (z == 0) {
          v *= QSCALE * uc[gm];
          oq[(size_t)gm * C_ + gn] = (unsigned short)f2bs(v);
        } else {
          ok[(size_t)gm * C_ + gn] = (unsigned short)f2bs(v);
        }
      }
    }
  }
}

// ---------------- output projection: out = ao@Wp^T + bp, f32 ----------------
// Tile 64(M) x 128(N), BK=64 -> 768 blocks = 3/CU.
// XCD swizzle: same-A-tile blocks (6 n) on one XCD.
__global__ __launch_bounds__(256, 4) void gemm_out(
    const unsigned short* __restrict__ ao, const unsigned short* __restrict__ wp,
    float* __restrict__ out, const float* __restrict__ bias) {
  __shared__ __align__(16) unsigned short Al[64 * 64];
  __shared__ __align__(16) unsigned short Bl[128 * 64];
  const int tid = threadIdx.x;
  const int w = tid >> 6, lane = tid & 63, quad = lane >> 4, id15 = lane & 15;
  const int wm = (w >> 1) << 5, wn = (w & 1) << 6;
  const int id = blockIdx.x;
  const int xcd = id & 7, slot = id >> 3;          // slot 0..95
  const int n0 = (slot % 6) << 7;
  const int m0 = (xcd * 16 + slot / 6) << 6;       // m-tile 0..127

  const int wb = tid & 192;
  const unsigned short* ap[2];
#pragma unroll
  for (int s = 0; s < 2; ++s) {                    // A: 64x64 tile, 512 granules
    int g = s * 256 + tid;
    int row = (g >> 2) & 63;
    int col = ((g >> 8) << 5) | ((g & 3) << 3);
    ap[s] = ao + (size_t)(m0 + row) * C_ + col;
  }
  const unsigned short* bp[4];
#pragma unroll
  for (int s = 0; s < 4; ++s) {                    // B: 128x64 tile, 1024 granules
    int g = s * 256 + tid;
    int row = (g >> 2) & 127;
    int col = ((g >> 9) << 5) | ((g & 3) << 3);
    bp[s] = wp + (size_t)(n0 + row) * C_ + col;
  }

  f32x4 acc[2][4] = {};
  for (int kt = 0; kt < C_; kt += 64) {
    __syncthreads();
#pragma unroll
    for (int s = 0; s < 2; ++s) async16(ap[s] + kt, Al + (s * 256 + wb) * 8);
#pragma unroll
    for (int s = 0; s < 4; ++s) async16(bp[s] + kt, Bl + (s * 256 + wb) * 8);
    __syncthreads();

#pragma unroll
    for (int kk = 0; kk < 2; ++kk) {
      bf16x8 af[2], bfr[4];
#pragma unroll
      for (int i = 0; i < 2; ++i)
        af[i]  = ldb8(&Al[kk * 2048 + (wm + i * 16 + id15) * 32 + quad * 8]);
#pragma unroll
      for (int j = 0; j < 4; ++j)
        bfr[j] = ldb8(&Bl[kk * 4096 + (wn + j * 16 + id15) * 32 + quad * 8]);
#pragma unroll
      for (int i = 0; i < 2; ++i)
#pragma unroll
        for (int j = 0; j < 4; ++j)
          acc[i][j] = mfma16(af[i], bfr[j], acc[i][j]);
    }
  }

#pragma unroll
  for (int i = 0; i < 2; ++i) {
#pragma unroll
    for (int j = 0; j < 4; ++j) {
#pragma unroll
      for (int r = 0; r < 4; ++r) {
        int gm = m0 + wm + i * 16 + quad * 4 + r;
        int gn = n0 + wn + j * 16 + id15;
        out[(size_t)gm * C_ + gn] = acc[i][j][r] + bias[gn];
      }
    }
  }
}

// ---------------- Flash attention v4 (R4/R9/R10-measured, ~84-86us) ---------------
// Coalesced K+V LDS double-buffer + raw s_barrier with lgkmcnt-only drain (next-tile
// loads stay in flight across the barrier), permlane32_swap P-repack, ones-MFMA
// row-sum, setprio around MFMA clusters.
// C/D layout (m74/m101): col=lane&31, row=(reg&3)+8*(reg>>2)+4*(lane>>5).
#define KSTR 72   // K/V LDS row stride (shorts): 144 B
#define VOFF (64 * KSTR)        // V panel offset within a buffer (shorts)
#define BUFO (2 * 64 * KSTR)    // double-buffer stride (shorts); LDS = 36864 B
__global__ __launch_bounds__(256, 3) void attn_kernel(
    const unsigned short* __restrict__ Q, const unsigned short* __restrict__ Kk,
    const unsigned short* __restrict__ Vt, unsigned short* __restrict__ O) {
  __shared__ __align__(16) unsigned short KV[2 * 2 * 64 * KSTR];  // 36864 B

  const int tid = threadIdx.x;
  const int w = tid >> 6, lane = tid & 63;
  const int i32 = lane & 31, hi = lane >> 5;
  const int id = blockIdx.x;
  const int xcd = id & 7, slot = id >> 3;          // slot 0..95
  const int bh = xcd * 6 + (slot >> 4);            // 0..47
  const int qt = slot & 15;
  const int b = bh / H_, h = bh % H_;
  const int q0 = qt * 128 + w * 32;                // 32 q-rows per wave

  // Q fragments (B-operand of QK^T): qf[s] = Q[q0+i32][d = s*16 + hi*8 + e]
  bf16x8 qf[4];
#pragma unroll
  for (int s = 0; s < 4; ++s)
    qf[s] = ldb8(Q + (size_t)(b * N_ + q0 + i32) * C_ + h * 64 + s * 16 + hi * 8);

  const uint4 onesu = {0x3F803F80u, 0x3F803F80u, 0x3F803F80u, 0x3F803F80u};
  const bf16x8 onesf = __builtin_bit_cast(bf16x8, onesu);

  f32x16 oacc0 = {}, oacc1 = {}, lacc = {};

  const size_t kbase = (size_t)(b * N_) * C_ + h * 64;
  const size_t vbase = (size_t)(b * C_ + h * 64) * N_;
  const int srow0 = tid >> 3, srow1 = 32 + (tid >> 3);
  const int sseg = (tid & 7) << 3;

  // Prologue: stage K+V tile 0 into buffer 0 (coalesced reg->LDS)
  {
    uint4 a0 = *(const uint4*)(Kk + kbase + (size_t)srow0 * C_ + sseg);
    uint4 a1 = *(const uint4*)(Kk + kbase + (size_t)srow1 * C_ + sseg);
    uint4 c0 = *(const uint4*)(Vt + vbase + (size_t)srow0 * N_ + sseg);
    uint4 c1 = *(const uint4*)(Vt + vbase + (size_t)srow1 * N_ + sseg);
    *(uint4*)&KV[srow0 * KSTR + sseg] = a0;
    *(uint4*)&KV[srow1 * KSTR + sseg] = a1;
    *(uint4*)&KV[VOFF + srow0 * KSTR + sseg] = c0;
    *(uint4*)&KV[VOFF + srow1 * KSTR + sseg] = c1;
  }

  int cur = 0;
  for (int kc = 0; kc < N_; kc += 64) {
    // next K+V tile -> regs, issued at iter top; they stay in flight across the
    // raw barrier (no vmcnt drain) and land in LDS after compute.
    const bool last = (kc + 64 >= N_);
    uint4 a0, a1, c0, c1;
    if (!last) {
      const int kcn = kc + 64;
      a0 = *(const uint4*)(Kk + kbase + (size_t)(kcn + srow0) * C_ + sseg);
      a1 = *(const uint4*)(Kk + kbase + (size_t)(kcn + srow1) * C_ + sseg);
      c0 = *(const uint4*)(Vt + vbase + (size_t)srow0 * N_ + kcn + sseg);
      c1 = *(const uint4*)(Vt + vbase + (size_t)srow1 * N_ + kcn + sseg);
    }

    // drain own LDS ops (prev writes + frag reads), then barrier. NO vmcnt drain.
    asm volatile("s_waitcnt lgkmcnt(0)" ::: "memory");
    __builtin_amdgcn_s_barrier();

    const unsigned short* Kc = KV + (cur ? BUFO : 0);
    const unsigned short* Vc = Kc + VOFF;
#pragma unroll
    for (int t = 0; t < 2; ++t) {        // k-row tile of 32 within the 64-row block
      // QK^T (S^T: rows = k, cols = q), contraction over D=64 in 4 ksteps
      f32x16 s16 = {};
      __builtin_amdgcn_s_setprio(1);
#pragma unroll
      for (int s = 0; s < 4; ++s) {
        bf16x8 kf = ldb8(Kc + (t * 32 + i32) * KSTR + s * 16 + hi * 8);
        s16 = mfma32(kf, qf[s], s16);
      }
      __builtin_amdgcn_s_setprio(0);
      // exp2 + RNE pack: dword j = P(k-pair start 8*(j>>1)+2*(j&1)+4*hi, col q=i32)
      unsigned Dw[8];
#pragma unroll
      for (int j = 0; j < 8; ++j) {
        float e0 = exp2f(s16[2 * j]);
        float e1 = exp2f(s16[2 * j + 1]);
        unsigned d;
        asm("v_cvt_pk_bf16_f32 %0, %1, %2" : "=v"(d) : "v"(e0), "v"(e1));
        Dw[j] = d;
      }
      // Half-swap repack into PV A-frags via permlane32_swap, then lsum + PV.
      __builtin_amdgcn_s_setprio(1);
#pragma unroll
      for (int sl = 0; sl < 2; ++sl) {
        const int bb = sl * 4;
        unsigned x0 = Dw[bb + 0], y0 = Dw[bb + 2];
        unsigned x1 = Dw[bb + 1], y1 = Dw[bb + 3];
        asm("v_permlane32_swap_b32 %0, %1" : "+v"(x0), "+v"(y0));
        asm("v_permlane32_swap_b32 %0, %1" : "+v"(x1), "+v"(y1));
        uint4 u;
        u.x = x0;                        // e0,e1: k = 16*sl + 8*hi + {0,1}
        u.y = x1;                        // e2,e3: +2
        u.z = y0;                        // e4,e5: +4
        u.w = y1;                        // e6,e7: +6
        bf16x8 pf = __builtin_bit_cast(bf16x8, u);
        lacc = mfma32(pf, onesf, lacc);  // row-sum on the matrix pipe
        bf16x8 v0 = ldb8(Vc + i32 * KSTR + (2 * t + sl) * 16 + hi * 8);
        bf16x8 v1 = ldb8(Vc + (32 + i32) * KSTR + (2 * t + sl) * 16 + hi * 8);
        oacc0 = mfma32(pf, v0, oacc0);
        oacc1 = mfma32(pf, v1, oacc1);
      }
      __builtin_amdgcn_s_setprio(0);
    }

    if (!last) {
      unsigned short* Kn = KV + (cur ? 0 : BUFO);
      *(uint4*)&Kn[srow0 * KSTR + sseg] = a0;
      *(uint4*)&Kn[srow1 * KSTR + sseg] = a1;
      *(uint4*)&Kn[VOFF + srow0 * KSTR + sseg] = c0;
      *(uint4*)&Kn[VOFF + srow1 * KSTR + sseg] = c1;
    }
    cur ^= 1;
  }

  // Epilogue: lacc reg r holds l for the same q-row as oacc reg r.
#pragma unroll
  for (int r = 0; r < 16; ++r) {
    float linv = 1.0f / lacc[r];
    int q = q0 + (r & 3) + 8 * (r >> 2) + 4 * hi;
    size_t base = (size_t)(b * N_ + q) * C_ + h * 64 + i32;
    O[base] = (unsigned short)f2bs(oacc0[r] * linv);
    O[base + 32] = (unsigned short)f2bs(oacc1[r] * linv);
  }
}

extern "C" void kernel_launch(void* const* d_in, const int* in_sizes, int n_in,
                              void* d_out, int out_size, void* d_ws, size_t ws_size,
                              hipStream_t stream) {
  const float* x_q = (const float*)d_in[0];
  const float* x_k = (const float*)d_in[1];
  const float* x_v = (const float*)d_in[2];
  const float* x_u = (const float*)d_in[3];
  const float* Wq  = (const float*)d_in[4];
  const float* Wk  = (const float*)d_in[5];
  const float* Wv  = (const float*)d_in[6];
  const float* Wp  = (const float*)d_in[7];
  const float* bp  = (const float*)d_in[8];

  char* ws = (char*)d_ws;
  size_t off = 0;
  auto alloc = [&](size_t bytes) {
    char* p = ws + off;
    off += (bytes + 255) & ~(size_t)255;
    return p;
  };
  unsigned short* wq16 = (unsigned short*)alloc((size_t)C_ * C_ * 2);
  unsigned short* wk16 = (unsigned short*)alloc((size_t)C_ * C_ * 2);
  unsigned short* wv16 = (unsigned short*)alloc((size_t)C_ * C_ * 2);
  unsigned short* wp16 = (unsigned short*)alloc((size_t)C_ * C_ * 2);
  float*          ucp  = (float*)alloc((size_t)B_ * N_ * 4);
  unsigned short* xq16 = (unsigned short*)alloc((size_t)B_ * N_ * C_ * 2);
  unsigned short* xk16 = (unsigned short*)alloc((size_t)B_ * N_ * C_ * 2);
  unsigned short* xv16 = (unsigned short*)alloc((size_t)B_ * N_ * C_ * 2);
  unsigned short* q_s  = (unsigned short*)alloc((size_t)B_ * N_ * C_ * 2);
  unsigned short* k_s  = (unsigned short*)alloc((size_t)B_ * N_ * C_ * 2);
  unsigned short* vT   = (unsigned short*)alloc((size_t)B_ * N_ * C_ * 2);
  unsigned short* ao   = (unsigned short*)alloc((size_t)B_ * N_ * C_ * 2);

  prep_kernel<<<dim3(7232), 256, 0, stream>>>(x_q, x_k, x_v, x_u, Wq, Wk, Wv, Wp,
                                              xq16, xk16, xv16,
                                              wq16, wk16, wv16, wp16, ucp);
  gemm_qkv<<<dim3(768), 256, 0, stream>>>(xq16, xk16, xv16, wq16, wk16, wv16,
                                          q_s, k_s, vT, ucp);
  attn_kernel<<<dim3(768), 256, 0, stream>>>(q_s, k_s, vT, ao);
  gemm_out<<<dim3(768), 256, 0, stream>>>(ao, wp16, (float*)d_out, bp);
}